// Round 9
// baseline (158.899 us; speedup 1.0000x reference)
//
#include <hip/hip_runtime.h>
#include <hip/hip_bf16.h>

// MoE MLP: x[1,2048,768] fp32, router_w[16,768], w1[768,12288], w2[12288,768]
// out[1,2048,768] fp32.  Experts: 8x512 + 8x1024, top-8, normalized.
// Dense bf16 GEMMs (reference is dense+masked); comb folded into H.
// GEMM core: m201-style 8-phase schedule. 256x256 tile, BK=64, 8 waves
// (2Mx4N, 128x64/wave). LDS = 2buf x (A 2x16KB + B 2x16KB halves) = 128KB.
// 4 phases/K-tile = output quadrants (0,0),(0,1),(1,1),(1,0); per phase:
// {ds_read subtile; stage 1 half-tile; barrier; lgkmcnt(0); setprio; 16 MFMA;
// setprio; barrier}. One counted vmcnt(4) per K-tile (phase 4) — loads stay
// in flight across barriers. Stage stream: ph1:A0(t+1) ph2:A1(t+1)
// ph3:B0(t+2) ph4:B1(t+2); write-after-read safe (A reads end ph3 -> A staged
// into OTHER buf at ph1-2; B reads end ph2 -> B staged into SAME buf ph3-4).
// XOR-swizzled LDS (T2), XCD-ownership mapping (T1), affine staging pointers.

#define T_TOK 2048
#define D_EMB 768
#define W_TOT 12288
#define N_EXP 16

typedef __attribute__((ext_vector_type(4))) float f32x4;
typedef __attribute__((ext_vector_type(8))) short bf16x8;

typedef __attribute__((address_space(1))) const unsigned int as1c_u32;
typedef __attribute__((address_space(3))) unsigned int as3_u32;

__device__ __forceinline__ void gload16(const void* g, void* l) {
  __builtin_amdgcn_global_load_lds((as1c_u32*)g, (as3_u32*)l, 16, 0, 0);
}

__device__ __forceinline__ unsigned short f2bf(float f) {
  __hip_bfloat16 h = __float2bfloat16(f);
  return *reinterpret_cast<unsigned short*>(&h);
}

__device__ __forceinline__ float gelu_f(float x) {
  // jax.nn.gelu default (approximate=True, tanh form)
  float x3 = x * x * x;
  float a = 0.7978845608028654f * __builtin_fmaf(0.044715f, x3, x);
  a = fminf(fmaxf(a, -20.f), 20.f);
  float e = __expf(-2.0f * a);
  float t = (1.0f - e) / (1.0f + e);
  return 0.5f * x * (1.0f + t);
}

// in fp32 [R][C] -> out bf16 [C][R]
__global__ __launch_bounds__(256) void transpose_cvt_kernel(
    const float* __restrict__ in, unsigned short* __restrict__ out, int R, int C) {
  __shared__ float tile[32][33];
  int c0 = blockIdx.x * 32;
  int r0 = blockIdx.y * 32;
  int i = threadIdx.x;
  {
    int r = i >> 3, c4 = (i & 7) * 4;
    float4 v = *(const float4*)(in + (size_t)(r0 + r) * C + c0 + c4);
    tile[r][c4 + 0] = v.x; tile[r][c4 + 1] = v.y;
    tile[r][c4 + 2] = v.z; tile[r][c4 + 3] = v.w;
  }
  __syncthreads();
  {
    int c = i >> 3, r4 = (i & 7) * 4;
    ushort4 o;
    o.x = f2bf(tile[r4 + 0][c]);
    o.y = f2bf(tile[r4 + 1][c]);
    o.z = f2bf(tile[r4 + 2][c]);
    o.w = f2bf(tile[r4 + 3][c]);
    *(ushort4*)(out + (size_t)(c0 + c) * R + r0 + r4) = o;
  }
}

// ---------------- router (also emits xb = bf16(x)) ----------------

__global__ __launch_bounds__(256) void router_kernel(
    const float* __restrict__ x, const float* __restrict__ rw,
    float* __restrict__ comb, unsigned short* __restrict__ xbout) {
  int tid = threadIdx.x, lane = tid & 63, w = tid >> 6;
  int t = blockIdx.x * 4 + w;
  const float* xr = x + (size_t)t * D_EMB;
  float xv[12];
#pragma unroll
  for (int i = 0; i < 12; ++i) xv[i] = xr[lane + 64 * i];
#pragma unroll
  for (int i = 0; i < 12; ++i)
    xbout[(size_t)t * D_EMB + lane + 64 * i] = f2bf(xv[i]);
  float lg[16];
#pragma unroll
  for (int e = 0; e < 16; ++e) {
    const float* we = rw + (size_t)e * D_EMB;
    float p = 0.f;
#pragma unroll
    for (int i = 0; i < 12; ++i) p = __builtin_fmaf(xv[i], we[lane + 64 * i], p);
#pragma unroll
    for (int off = 32; off >= 1; off >>= 1) p += __shfl_xor(p, off, 64);
    lg[e] = p;
  }
  float mx = lg[0];
#pragma unroll
  for (int e = 1; e < 16; ++e) mx = fmaxf(mx, lg[e]);
  float ex[16];
#pragma unroll
  for (int e = 0; e < 16; ++e) ex[e] = __expf(lg[e] - mx);
  float selsum = 0.f, myval = 0.f;
#pragma unroll
  for (int e = 0; e < 16; ++e) {
    int rank = 0;
#pragma unroll
    for (int e2 = 0; e2 < 16; ++e2)
      rank += (ex[e2] > ex[e]) || (ex[e2] == ex[e] && e2 < e);
    bool sel = rank < 8;
    float v = sel ? ex[e] : 0.f;
    selsum += v;
    if (e == lane) myval = v;
  }
  if (lane < 16) comb[(size_t)t * N_EXP + lane] = myval / selsum;
}

// --------------- 8-wave 8-phase GEMM, 256x256 tile, BK=64 ---------------
// MAP: 0 = gemm1 XCD-owns-N (grid 384), 1 = gemm2 XCD=zt (grid 192).
// EPI: 1 = gelu*comb -> bf16 H, 0 = fp32 partial.

template <int EPI, int MAP>
__global__ __launch_bounds__(512, 2) void gemm_kernel(
    const unsigned short* __restrict__ Ag, const unsigned short* __restrict__ Bg,
    int lda, int ldb, int ntiles, int kchunk,
    const float* __restrict__ comb, unsigned short* __restrict__ hout,
    float* __restrict__ pout) {
  __shared__ __align__(16) char smem[131072];  // A 2buf x 32KB | B 2buf x 32KB

  const int tid = threadIdx.x;
  const int lane = tid & 63;
  const int wid = tid >> 6;
  const int wr = wid >> 2;        // 0..1  (M half: 128 rows = A half wr)
  const int wc = wid & 3;         // 0..3  (N quarter: 64 cols; B half wc>>1)

  int mt, nt, zt;
  {
    int bid = blockIdx.x;
    if (MAP == 0) {               // gemm1: XCD owns 6 N-panels, M fastest
      int xcd = bid & 7, r = bid >> 3;        // r in 0..47
      nt = xcd * 6 + (r >> 3); mt = r & 7; zt = 0;
    } else {                      // gemm2: XCD = K-split
      zt = bid & 7; int r = bid >> 3;         // r in 0..23
      nt = r % 3; mt = r / 3;
    }
  }
  const int rm0 = mt * 256;
  const int cn0 = nt * 256;
  const int kbeg = zt * kchunk;

  // ---- staging pointers (pre-swizzled source, rule #21), affine ----
  // Half-tile = 128 rows x 64 k bf16 = 16KB = 2 gloads (512 thr x 16B).
  auto gsrcA = [&](int h, int j) {
    int off = j * 8192 + tid * 16;
    int row = off >> 7, inrow = off & 127;
    int scol = inrow ^ ((row & 7) << 4);
    return (const char*)Ag +
           ((size_t)(rm0 + h * 128 + row) * lda + kbeg) * 2 + scol;
  };
  auto gsrcB = [&](int h, int j) {
    int off = j * 8192 + tid * 16;
    int row = off >> 7, inrow = off & 127;
    int scol = inrow ^ ((row & 7) << 4);
    return (const char*)Bg +
           ((size_t)(cn0 + h * 128 + row) * ldb + kbeg) * 2 + scol;
  };
  const char* qA00 = gsrcA(0, 0); const char* qA01 = gsrcA(0, 1);
  const char* qA10 = gsrcA(1, 0); const char* qA11 = gsrcA(1, 1);
  const char* qB00 = gsrcB(0, 0); const char* qB01 = gsrcB(0, 1);
  const char* qB10 = gsrcB(1, 0); const char* qB11 = gsrcB(1, 1);

  // ---- precomputed LDS read bases (buffer 0, bytes) ----
  const int lswz = (lane & 7) << 4;
  const int colk0 = (((lane >> 4) & 3) * 16) ^ lswz;
  const int colk1 = (64 + ((lane >> 4) & 3) * 16) ^ lswz;
  // A: half wr, local row m*16+(lane&15) (+qm*64), 128B rows
  const int ab0 = wr * 16384 + (lane & 15) * 128 + colk0;
  const int ab1 = wr * 16384 + (lane & 15) * 128 + colk1;
  // B: half wc>>1, local row (wc&1)*64 + qn*32 + n*16 + (lane&15)
  const int bb0 = 65536 + (wc >> 1) * 16384 + ((wc & 1) * 64 + (lane & 15)) * 128 + colk0;
  const int bb1 = 65536 + (wc >> 1) * 16384 + ((wc & 1) * 64 + (lane & 15)) * 128 + colk1;

  f32x4 acc[8][4];
#pragma unroll
  for (int m = 0; m < 8; ++m)
#pragma unroll
    for (int n = 0; n < 4; ++n) acc[m][n] = (f32x4){0.f, 0.f, 0.f, 0.f};

  // ---- prologue: A(0),B(0) then B... stream-consistent pre-issue ----
  // issue order: A0(0) A1(0) B0(0) B1(0) B0(1) B1(1) = 12 loads
  gload16(qA00, smem + 0 + wid * 1024);
  gload16(qA01, smem + 8192 + wid * 1024);
  gload16(qA10, smem + 16384 + wid * 1024);
  gload16(qA11, smem + 16384 + 8192 + wid * 1024);
  gload16(qB00, smem + 65536 + wid * 1024);
  gload16(qB01, smem + 65536 + 8192 + wid * 1024);
  gload16(qB10, smem + 65536 + 16384 + wid * 1024);
  gload16(qB11, smem + 65536 + 16384 + 8192 + wid * 1024);
  gload16(qB00 + 128, smem + 65536 + 32768 + wid * 1024);
  gload16(qB01 + 128, smem + 65536 + 32768 + 8192 + wid * 1024);
  gload16(qB10 + 128, smem + 65536 + 32768 + 16384 + wid * 1024);
  gload16(qB11 + 128, smem + 65536 + 32768 + 16384 + 8192 + wid * 1024);
  // steady-state pointers: A targets tile 1 (staged ph1-2), B targets tile 2
  const char* pA00 = qA00 + 128; const char* pA01 = qA01 + 128;
  const char* pA10 = qA10 + 128; const char* pA11 = qA11 + 128;
  const char* pB00 = qB00 + 256; const char* pB01 = qB01 + 256;
  const char* pB10 = qB10 + 256; const char* pB11 = qB11 + 256;
  asm volatile("s_waitcnt vmcnt(4)" ::: "memory");  // A(0),B(0) landed
  __builtin_amdgcn_s_barrier();
  __builtin_amdgcn_sched_barrier(0);

  bf16x8 a[4][2], b0[2][2], b1[2][2];
  int cb = 0;
  for (int t = 0; t < ntiles; ++t) {
    const int nb = cb ^ 32768;

    // ===== phase 1: read a(qm0) + b0(qn0); stage A0(t+1); MFMA q(0,0) =====
#pragma unroll
    for (int m = 0; m < 4; ++m) {
      a[m][0] = *(const bf16x8*)(smem + cb + ab0 + m * 2048);
      a[m][1] = *(const bf16x8*)(smem + cb + ab1 + m * 2048);
    }
#pragma unroll
    for (int n = 0; n < 2; ++n) {
      b0[n][0] = *(const bf16x8*)(smem + cb + bb0 + n * 2048);
      b0[n][1] = *(const bf16x8*)(smem + cb + bb1 + n * 2048);
    }
    gload16(pA00, smem + nb + wid * 1024);
    gload16(pA01, smem + nb + 8192 + wid * 1024);
    pA00 += 128; pA01 += 128;
    __builtin_amdgcn_s_barrier();
    asm volatile("s_waitcnt lgkmcnt(0)" ::: "memory");
    __builtin_amdgcn_sched_barrier(0);
    __builtin_amdgcn_s_setprio(1);
#pragma unroll
    for (int m = 0; m < 4; ++m)
#pragma unroll
      for (int n = 0; n < 2; ++n)
#pragma unroll
        for (int kk = 0; kk < 2; ++kk)
          acc[m][n] = __builtin_amdgcn_mfma_f32_16x16x32_bf16(
              a[m][kk], b0[n][kk], acc[m][n], 0, 0, 0);
    __builtin_amdgcn_s_setprio(0);
    __builtin_amdgcn_s_barrier();
    __builtin_amdgcn_sched_barrier(0);

    // ===== phase 2: read b1(qn1); stage A1(t+1); MFMA q(0,1) =====
#pragma unroll
    for (int n = 0; n < 2; ++n) {
      b1[n][0] = *(const bf16x8*)(smem + cb + bb0 + 4096 + n * 2048);
      b1[n][1] = *(const bf16x8*)(smem + cb + bb1 + 4096 + n * 2048);
    }
    gload16(pA10, smem + nb + 16384 + wid * 1024);
    gload16(pA11, smem + nb + 16384 + 8192 + wid * 1024);
    pA10 += 128; pA11 += 128;
    __builtin_amdgcn_s_barrier();
    asm volatile("s_waitcnt lgkmcnt(0)" ::: "memory");
    __builtin_amdgcn_sched_barrier(0);
    __builtin_amdgcn_s_setprio(1);
#pragma unroll
    for (int m = 0; m < 4; ++m)
#pragma unroll
      for (int n = 0; n < 2; ++n)
#pragma unroll
        for (int kk = 0; kk < 2; ++kk)
          acc[m][2 + n] = __builtin_amdgcn_mfma_f32_16x16x32_bf16(
              a[m][kk], b1[n][kk], acc[m][2 + n], 0, 0, 0);
    __builtin_amdgcn_s_setprio(0);
    __builtin_amdgcn_s_barrier();
    __builtin_amdgcn_sched_barrier(0);

    // ===== phase 3: read a(qm1); stage B0(t+2); MFMA q(1,1) =====
#pragma unroll
    for (int m = 0; m < 4; ++m) {
      a[m][0] = *(const bf16x8*)(smem + cb + ab0 + 8192 + m * 2048);
      a[m][1] = *(const bf16x8*)(smem + cb + ab1 + 8192 + m * 2048);
    }
    gload16(pB00, smem + 65536 + cb + wid * 1024);
    gload16(pB01, smem + 65536 + cb + 8192 + wid * 1024);
    pB00 += 128; pB01 += 128;
    __builtin_amdgcn_s_barrier();
    asm volatile("s_waitcnt lgkmcnt(0)" ::: "memory");
    __builtin_amdgcn_sched_barrier(0);
    __builtin_amdgcn_s_setprio(1);
#pragma unroll
    for (int m = 0; m < 4; ++m)
#pragma unroll
      for (int n = 0; n < 2; ++n)
#pragma unroll
        for (int kk = 0; kk < 2; ++kk)
          acc[4 + m][2 + n] = __builtin_amdgcn_mfma_f32_16x16x32_bf16(
              a[m][kk], b1[n][kk], acc[4 + m][2 + n], 0, 0, 0);
    __builtin_amdgcn_s_setprio(0);
    __builtin_amdgcn_s_barrier();
    __builtin_amdgcn_sched_barrier(0);

    // ===== phase 4: stage B1(t+2); vmcnt(4); MFMA q(1,0) =====
    gload16(pB10, smem + 65536 + cb + 16384 + wid * 1024);
    gload16(pB11, smem + 65536 + cb + 16384 + 8192 + wid * 1024);
    pB10 += 128; pB11 += 128;
    asm volatile("s_waitcnt vmcnt(4)" ::: "memory");  // all of t+1 landed
    __builtin_amdgcn_s_barrier();
    __builtin_amdgcn_sched_barrier(0);
    __builtin_amdgcn_s_setprio(1);
#pragma unroll
    for (int m = 0; m < 4; ++m)
#pragma unroll
      for (int n = 0; n < 2; ++n)
#pragma unroll
        for (int kk = 0; kk < 2; ++kk)
          acc[4 + m][n] = __builtin_amdgcn_mfma_f32_16x16x32_bf16(
              a[m][kk], b0[n][kk], acc[4 + m][n], 0, 0, 0);
    __builtin_amdgcn_s_setprio(0);
    __builtin_amdgcn_s_barrier();
    __builtin_amdgcn_sched_barrier(0);

    cb = nb;
  }

  asm volatile("s_waitcnt vmcnt(0)" ::: "memory");  // drain tail stages
  __syncthreads();

  // ---- epilogue ----
  const int r0 = (lane >> 4) * 4;
  const int cl = lane & 15;
  if constexpr (EPI == 1) {
    float* Cwf = (float*)smem;   // reuse staging LDS: [256 rows][16 experts]
    {
      int row = tid >> 1, c8 = (tid & 1) * 8;
      const float* s = comb + (size_t)(rm0 + row) * N_EXP + c8;
      *(float4*)&Cwf[row * 16 + c8] = *(const float4*)s;
      *(float4*)&Cwf[row * 16 + c8 + 4] = *(const float4*)(s + 4);
    }
    __syncthreads();
#pragma unroll
    for (int n = 0; n < 4; ++n) {
      int colg = cn0 + wc * 64 + n * 16 + cl;
      int e = (colg < 4096) ? (colg >> 9) : (8 + ((colg - 4096) >> 10));
#pragma unroll
      for (int m = 0; m < 8; ++m) {
        int rl = wr * 128 + m * 16 + r0;
#pragma unroll
        for (int r = 0; r < 4; ++r) {
          float v = gelu_f(acc[m][n][r]) * Cwf[(rl + r) * 16 + e];
          hout[(size_t)(rm0 + rl + r) * W_TOT + colg] = f2bf(v);
        }
      }
    }
  } else {
    float* pz = pout + (size_t)zt * T_TOK * D_EMB;
#pragma unroll
    for (int n = 0; n < 4; ++n) {
      int colg = cn0 + wc * 64 + n * 16 + cl;
#pragma unroll
      for (int m = 0; m < 8; ++m) {
        int rl = wr * 128 + m * 16 + r0;
#pragma unroll
        for (int r = 0; r < 4; ++r)
          pz[(size_t)(rm0 + rl + r) * D_EMB + colg] = acc[m][n][r];
      }
    }
  }
}

__global__ __launch_bounds__(256) void reduce_kernel(
    const float* __restrict__ partial, float* __restrict__ out, int splits) {
  int i = (blockIdx.x * 256 + threadIdx.x) * 4;
  if (i >= T_TOK * D_EMB) return;
  float4 s = *(const float4*)(partial + i);
  for (int sp = 1; sp < splits; ++sp) {
    float4 v = *(const float4*)(partial + (size_t)sp * T_TOK * D_EMB + i);
    s.x += v.x; s.y += v.y; s.z += v.z; s.w += v.w;
  }
  *(float4*)(out + i) = s;
}

// ---------------- launcher ----------------

extern "C" void kernel_launch(void* const* d_in, const int* in_sizes, int n_in,
                              void* d_out, int out_size, void* d_ws, size_t ws_size,
                              hipStream_t stream) {
  const float* x = (const float*)d_in[0];
  const float* router_w = (const float*)d_in[1];
  const float* w1 = (const float*)d_in[2];
  const float* w2 = (const float*)d_in[3];
  float* out = (float*)d_out;

  char* ws = (char*)d_ws;
  size_t off = 0;
  auto alloc = [&](size_t bytes) {
    char* p = ws + off;
    off += (bytes + 255) & ~(size_t)255;
    return p;
  };
  unsigned short* xb  = (unsigned short*)alloc((size_t)T_TOK * D_EMB * 2);
  unsigned short* w1t = (unsigned short*)alloc((size_t)W_TOT * D_EMB * 2);
  unsigned short* w2t = (unsigned short*)alloc((size_t)D_EMB * W_TOT * 2);
  unsigned short* h   = (unsigned short*)alloc((size_t)T_TOK * W_TOT * 2);
  float* comb         = (float*)alloc((size_t)T_TOK * N_EXP * 4);

  const int splits = 8;                     // grid 192; kchunk 1536 (24 tiles)
  float* partial = (float*)alloc((size_t)splits * T_TOK * D_EMB * 4);
  int kchunk = W_TOT / splits;

  transpose_cvt_kernel<<<dim3(W_TOT / 32, D_EMB / 32), 256, 0, stream>>>(w1, w1t, D_EMB, W_TOT);
  transpose_cvt_kernel<<<dim3(D_EMB / 32, W_TOT / 32), 256, 0, stream>>>(w2, w2t, W_TOT, D_EMB);
  router_kernel<<<T_TOK / 4, 256, 0, stream>>>(x, router_w, comb, xb);

  // GEMM1: H = gelu(X W1) * comb ; grid 384 = 8 XCD x (6 N x 8 M)
  gemm_kernel<1, 0><<<384, 512, 0, stream>>>(
      xb, w1t, D_EMB, D_EMB, D_EMB / 64, D_EMB, comb, h, nullptr);

  // GEMM2: OUT = H W2 ; grid 192 = 8 splits x (3 N x 8 M)
  gemm_kernel<0, 1><<<192, 512, 0, stream>>>(
      h, w2t, W_TOT, W_TOT, kchunk / 64, kchunk, nullptr, nullptr, partial);

  reduce_kernel<<<(T_TOK * D_EMB) / 1024, 256, 0, stream>>>(partial, out, splits);
}